// Round 11
// baseline (2344.522 us; speedup 1.0000x reference)
//
#include <hip/hip_runtime.h>
#include <stdint.h>
#include <stddef.h>

#define S_LEN 2048
#define BATCH 32
#define NIN   256
#define NH    256
#define NG    768   // 3*NH
#define GRUB  32    // gru role blocks
#define XPB   2048  // xproj role blocks (32 rows = 1 step each)

typedef _Float16 half2_t __attribute__((ext_vector_type(2)));
typedef int      int8v   __attribute__((ext_vector_type(8)));
typedef int      int4v   __attribute__((ext_vector_type(4)));

#if __has_builtin(__builtin_amdgcn_exp2f)
#define EXP2F(x) __builtin_amdgcn_exp2f(x)
#else
#define EXP2F(x) exp2f(x)
#endif

static __device__ __forceinline__ float fdot2(half2_t a, half2_t b, float c) {
  return __builtin_amdgcn_fdot2(a, b, c, false);
}
static __device__ __forceinline__ half2_t pack2(float lo, float hi) {
  half2_t r; r[0] = (_Float16)lo; r[1] = (_Float16)hi; return r;
}
static __device__ __forceinline__ float sigmoid_fast(float x) {
  float e = EXP2F(-1.44269504088896340736f * x);
  return 1.0f / (1.0f + e);
}
static __device__ __forceinline__ float tanh_fast(float x) {
  float e = EXP2F(2.88539008177792681472f * x);
  return 1.0f - 2.0f / (1.0f + e);
}
static __device__ __forceinline__ float dpp_xor1(float v) {
  return __builtin_bit_cast(float,
    __builtin_amdgcn_mov_dpp(__builtin_bit_cast(int, v), 0xB1, 0xF, 0xF, true));
}
static __device__ __forceinline__ float dpp_xor2(float v) {
  return __builtin_bit_cast(float,
    __builtin_amdgcn_mov_dpp(__builtin_bit_cast(int, v), 0x4E, 0xF, 0xF, true));
}

// 36 ready-flags in one shot, device-coherent (sc0 sc1 bypasses L1+XCD-L2),
// single base + literal offsets, ONE vmcnt(0) drain per poll.
static __device__ __forceinline__ int flags_all36(const int* p) {
  int4v a0, a1, a2, a3, a4, a5, a6, a7, a8;
  asm volatile("global_load_dwordx4 %0, %9, off sc0 sc1\n"
               "global_load_dwordx4 %1, %9, off offset:16 sc0 sc1\n"
               "global_load_dwordx4 %2, %9, off offset:32 sc0 sc1\n"
               "global_load_dwordx4 %3, %9, off offset:48 sc0 sc1\n"
               "global_load_dwordx4 %4, %9, off offset:64 sc0 sc1\n"
               "global_load_dwordx4 %5, %9, off offset:80 sc0 sc1\n"
               "global_load_dwordx4 %6, %9, off offset:96 sc0 sc1\n"
               "global_load_dwordx4 %7, %9, off offset:112 sc0 sc1\n"
               "global_load_dwordx4 %8, %9, off offset:128 sc0 sc1\n"
               "s_waitcnt vmcnt(0)"
               : "=v"(a0), "=v"(a1), "=v"(a2), "=v"(a3), "=v"(a4),
                 "=v"(a5), "=v"(a6), "=v"(a7), "=v"(a8)
               : "v"(p)
               : "memory");
  int all = a0.x & a0.y & a0.z & a0.w;
  all &= a1.x & a1.y & a1.z & a1.w;
  all &= a2.x & a2.y & a2.z & a2.w;
  all &= a3.x & a3.y & a3.z & a3.w;
  all &= a4.x & a4.y & a4.z & a4.w;
  all &= a5.x & a5.y & a5.z & a5.w;
  all &= a6.x & a6.y & a6.z & a6.w;
  all &= a7.x & a7.y & a7.z & a7.w;
  all &= a8.x & a8.y & a8.z & a8.w;
  return all;
}
#define FLAGWAIT36(BASEP) do {                                                \
    while (!flags_all36(BASEP)) __builtin_amdgcn_s_sleep(16);                 \
  } while (0)

// bit-cast helpers: element extracts use LITERAL indices -> pure SSA
#define BH(x)    __builtin_bit_cast(half2_t, (x))
#define BW(W, e) __builtin_bit_cast(half2_t, (int)((W)[e]))
#define P2I(a, b) __builtin_bit_cast(int, pack2((a), (b)))

// one 16B operand chunk (4 half2) against 6 row-slices (2j x 3 gates).
// Weight as src0. Accumulator reuse distance 6 -> no VALU dep stalls.
// U* are int8v; o in {0,4} selects which half of the tuple.
#define DOT6(q, U0, U1, U2, U3, U4, U5, o) do {                               \
    a0 = fdot2(BW(U0,(o)+0), BH(q.x), a0); a1 = fdot2(BW(U1,(o)+0), BH(q.x), a1);\
    a2 = fdot2(BW(U2,(o)+0), BH(q.x), a2); a3 = fdot2(BW(U3,(o)+0), BH(q.x), a3);\
    a4 = fdot2(BW(U4,(o)+0), BH(q.x), a4); a5 = fdot2(BW(U5,(o)+0), BH(q.x), a5);\
    a0 = fdot2(BW(U0,(o)+1), BH(q.y), a0); a1 = fdot2(BW(U1,(o)+1), BH(q.y), a1);\
    a2 = fdot2(BW(U2,(o)+1), BH(q.y), a2); a3 = fdot2(BW(U3,(o)+1), BH(q.y), a3);\
    a4 = fdot2(BW(U4,(o)+1), BH(q.y), a4); a5 = fdot2(BW(U5,(o)+1), BH(q.y), a5);\
    a0 = fdot2(BW(U0,(o)+2), BH(q.z), a0); a1 = fdot2(BW(U1,(o)+2), BH(q.z), a1);\
    a2 = fdot2(BW(U2,(o)+2), BH(q.z), a2); a3 = fdot2(BW(U3,(o)+2), BH(q.z), a3);\
    a4 = fdot2(BW(U4,(o)+2), BH(q.z), a4); a5 = fdot2(BW(U5,(o)+2), BH(q.z), a5);\
    a0 = fdot2(BW(U0,(o)+3), BH(q.w), a0); a1 = fdot2(BW(U1,(o)+3), BH(q.w), a1);\
    a2 = fdot2(BW(U2,(o)+3), BH(q.w), a2); a3 = fdot2(BW(U3,(o)+3), BH(q.w), a3);\
    a4 = fdot2(BW(U4,(o)+3), BH(q.w), a4); a5 = fdot2(BW(U5,(o)+3), BH(q.w), a5);\
  } while (0)

#define LDW8(W, o) do {                                                       \
    int4 t0 = wsrc[(o)], t1 = wsrc[(o) + 1];                                  \
    W = (int8v){t0.x, t0.y, t0.z, t0.w, t1.x, t1.y, t1.z, t1.w};              \
  } while (0)

// 24 x int8v weight tuples (8-aligned granules pack the register file far
// better than 16-aligned int16v -- R10 diagnosis: 12x16 tuples + 259-reg
// peak forced the allocator to shunt all weights to AGPRs, costing one
// v_accvgpr_read per weight use per step since VOP3P fdot2 cannot source
// AGPRs). ONE 24-operand pin (R4's proven single-statement shape).
#define LOADPIN_W(SRC)                                                        \
  int8v W00, W01, W02, W03, W10, W11, W12, W13, W20, W21, W22, W23,           \
        W30, W31, W32, W33, W40, W41, W42, W43, W50, W51, W52, W53;           \
  {                                                                           \
    const int4* wsrc = (const int4*)(SRC);                                    \
    LDW8(W00, 0);  LDW8(W01, 2);  LDW8(W02, 4);  LDW8(W03, 6);                \
    LDW8(W10, 8);  LDW8(W11, 10); LDW8(W12, 12); LDW8(W13, 14);               \
    LDW8(W20, 16); LDW8(W21, 18); LDW8(W22, 20); LDW8(W23, 22);               \
    LDW8(W30, 24); LDW8(W31, 26); LDW8(W32, 28); LDW8(W33, 30);               \
    LDW8(W40, 32); LDW8(W41, 34); LDW8(W42, 36); LDW8(W43, 38);               \
    LDW8(W50, 40); LDW8(W51, 42); LDW8(W52, 44); LDW8(W53, 46);               \
  }                                                                           \
  asm volatile("" : "+v"(W00), "+v"(W01), "+v"(W02), "+v"(W03),               \
                    "+v"(W10), "+v"(W11), "+v"(W12), "+v"(W13),               \
                    "+v"(W20), "+v"(W21), "+v"(W22), "+v"(W23),               \
                    "+v"(W30), "+v"(W31), "+v"(W32), "+v"(W33),               \
                    "+v"(W40), "+v"(W41), "+v"(W42), "+v"(W43),               \
                    "+v"(W50), "+v"(W51), "+v"(W52), "+v"(W53));

// parity-early quad reduction (bit-identical to quad_sum tree, 6 fewer VALU)
#define QREDUCE(MVR, MVZ, MVN) do {                                           \
    float b0 = a0 + dpp_xor1(a0), b1 = a1 + dpp_xor1(a1);                     \
    float b2 = a2 + dpp_xor1(a2), b3 = a3 + dpp_xor1(a3);                     \
    float b4 = a4 + dpp_xor1(a4), b5 = a5 + dpp_xor1(a5);                     \
    float xr_ = jj ? b1 : b0, xz_ = jj ? b3 : b2, xn_ = jj ? b5 : b4;         \
    MVR = xr_ + dpp_xor2(xr_);                                                \
    MVZ = xz_ + dpp_xor2(xz_);                                                \
    MVN = xn_ + dpp_xor2(xn_);                                                \
  } while (0)

// ---------------- prep: weights + flag init (unchanged layout) --------------
__global__ __launch_bounds__(256) void prep_w_kernel(const float* __restrict__ W_ih,
                                                     const float* __restrict__ W_hh,
                                                     const float* __restrict__ b_ih,
                                                     const float* __restrict__ b_hh,
                                                     half2_t* __restrict__ whh3,
                                                     half2_t* __restrict__ wih3,
                                                     float* __restrict__ bias,
                                                     int* __restrict__ flags) {
  int idx = blockIdx.x * 256 + threadIdx.x;
  if (idx < 128 * NG) {
    int tid = idx / 192;
    int r   = idx - tid * 192;
    int d   = r >> 5, kk = r & 31;
    int gate = d >> 1, jj = d & 1;
    int c  = tid & 3, j1 = tid >> 2;
    int row = gate * NH + 2 * j1 + jj;
    int col = 64 * c + 2 * kk;
    whh3[idx] = pack2(W_hh[(size_t)row * NH + col], W_hh[(size_t)row * NH + col + 1]);
  } else if (idx < 2 * 128 * NG) {
    int i2  = idx - 128 * NG;
    int tid = i2 / 192;
    int r   = i2 - tid * 192;
    int d   = r >> 5, kk = r & 31;
    int gate = d >> 1, jj = d & 1;
    int c  = tid & 3, j1 = tid >> 2;
    int row = gate * NH + 2 * j1 + jj;
    int col = 64 * c + 2 * kk;
    wih3[i2] = pack2(W_ih[(size_t)row * NIN + col], W_ih[(size_t)row * NIN + col + 1]);
  } else if (idx < 2 * 128 * NG + NG) {
    int g = idx - 2 * 128 * NG;
    bias[g] = b_ih[g] + b_hh[g];
  } else if (idx < 2 * 128 * NG + NG + XPB + 16) {
    int k = idx - (2 * 128 * NG + NG);
    flags[k] = (k < XPB) ? 0 : 1;   // 16 sentinels for the 36-wide check
  }
}

// ---------------- fused: gru (blocks 0..31) + xproj (blocks 32..2079) -------
// R11: weights -> VGPRs. R10 accounting: 192 fdot2/thread/step needs 768
// cyc/SIMD but measured VALU issue ~2200 -> ~192 extra insts/thread = one
// v_accvgpr_read per weight dword per step (VOP3P can't source AGPR; R7's
// operand swap null confirms position-independence). Root cause: peak live
// demand 259 > 256 with 16-aligned tuples -> allocator evicted weights to
// AGPRs. Fix: int8v granules + q streamed 2-pairs-ahead (live q 32->16 regs,
// peak ~239). Math order identical (kk-ascending per acc) -> bit-identical.
__global__
__attribute__((amdgpu_flat_work_group_size(512, 512), amdgpu_waves_per_eu(2, 2)))
void fused_kernel(const float* __restrict__ inf,
                  const half2_t* __restrict__ wih3,
                  const float* __restrict__ bias,
                  float* __restrict__ xp,
                  const half2_t* __restrict__ whh3,
                  float* __restrict__ out,
                  int* __restrict__ flags) {
  const int tid = threadIdx.x;
  const int c   = tid & 3;        // K-quarter
  const int j1  = tid >> 2;       // j-pair index 0..127
  const int jj  = c & 1;          // owned j parity
  const int jmine = 2 * j1 + jj;

  if (blockIdx.x >= GRUB) {
    // ---------------- xproj role: one time-step (32 rows) ----------------
    const int xb = (int)blockIdx.x - GRUB;
    LOADPIN_W(wih3 + (size_t)tid * 192);
    const float bgr = bias[jmine], bgz = bias[NH + jmine], bgn = bias[2 * NH + jmine];
    const float4* fr = (const float4*)(inf + (size_t)xb * 32 * NIN + c * 64);
    float* xo = xp + (size_t)xb * 32 * NG + jmine;
    for (int rr = 0; rr < 32; ++rr) {
      float a0 = 0.f, a1 = 0.f, a2 = 0.f, a3 = 0.f, a4 = 0.f, a5 = 0.f;
      float4 g0, g1; int4 q;
#define XB(IDX, U0, U1, U2, U3, U4, U5, OFF)                                  \
      g0 = fr[2 * (IDX)]; g1 = fr[2 * (IDX) + 1];                             \
      q.x = P2I(g0.x, g0.y); q.y = P2I(g0.z, g0.w);                           \
      q.z = P2I(g1.x, g1.y); q.w = P2I(g1.z, g1.w);                           \
      DOT6(q, U0, U1, U2, U3, U4, U5, OFF);
      XB(0, W00, W10, W20, W30, W40, W50, 0)
      XB(1, W00, W10, W20, W30, W40, W50, 4)
      XB(2, W01, W11, W21, W31, W41, W51, 0)
      XB(3, W01, W11, W21, W31, W41, W51, 4)
      XB(4, W02, W12, W22, W32, W42, W52, 0)
      XB(5, W02, W12, W22, W32, W42, W52, 4)
      XB(6, W03, W13, W23, W33, W43, W53, 0)
      XB(7, W03, W13, W23, W33, W43, W53, 4)
#undef XB
      float mvr, mvz, mvn;
      QREDUCE(mvr, mvz, mvn);
      if (c < 2) {
        float vr = mvr + bgr, vz = mvz + bgz, vn = mvn + bgn;
        // write-through to MALL: no dirty XCD-L2 lines, nothing to wbl2 later
        asm volatile("global_store_dword %0, %1, off sc0 sc1\n"
                     "global_store_dword %0, %2, off offset:1024 sc0 sc1\n"
                     "global_store_dword %0, %3, off offset:2048 sc0 sc1"
                     :: "v"(xo), "v"(vr), "v"(vz), "v"(vn) : "memory");
      }
      fr += 64;   // next row (256 floats)
      xo += NG;
    }
    __syncthreads();   // per-wave vmcnt(0): all sc0sc1 xp stores MALL-acked
    if (tid == 0) {    // plain device-visible flag store; NO wbl2
      int one = 1;
      asm volatile("global_store_dword %0, %1, off sc0 sc1"
                   :: "v"(&flags[xb]), "v"(one) : "memory");
    }
    return;
  }

  // ---------------- gru role: one batch chain ----------------
  const int b = blockIdx.x;
  LOADPIN_W(whh3 + (size_t)tid * 192);

  // 2 buffers x 4 chunks x 144 B (chunk = 64 f16 + 16 B pad) = 1152 B
  __shared__ __attribute__((aligned(16))) char smh[1152];
  if (tid < 288) ((int*)smh)[tid] = 0;

  FLAGWAIT36(flags);   // rows 0..35 ready: covers preload + window-0 prefetches

  const float* xq = xp + (size_t)b * NG + jmine;
  float xr_c = xq[0], xz_c = xq[NH], xn_c = xq[2 * NH];
  xq += (size_t)BATCH * NG;
  float* op = out + (size_t)b * NH + jmine;

  const int wofs = 144 * (jmine >> 6) + 2 * (jmine & 63);

  float h = 0.f;
  __syncthreads();

#define GSTEP(RB, WB) do {                                                    \
    float xr_n = xq[0], xz_n = xq[NH], xn_n = xq[2 * NH];                     \
    const int4* hb4 = (const int4*)(smh + (RB) + c * 144);                    \
    float a0 = 0.f, a1 = 0.f, a2 = 0.f, a3 = 0.f, a4 = 0.f, a5 = 0.f;        \
    int4 qa0 = hb4[0], qa1 = hb4[1];                                          \
    int4 qb0 = hb4[2], qb1 = hb4[3];                                          \
    DOT6(qa0, W00, W10, W20, W30, W40, W50, 0);                               \
    DOT6(qa1, W00, W10, W20, W30, W40, W50, 4);                               \
    qa0 = hb4[4]; qa1 = hb4[5];                                               \
    DOT6(qb0, W01, W11, W21, W31, W41, W51, 0);                               \
    DOT6(qb1, W01, W11, W21, W31, W41, W51, 4);                               \
    qb0 = hb4[6]; qb1 = hb4[7];                                               \
    DOT6(qa0, W02, W12, W22, W32, W42, W52, 0);                               \
    DOT6(qa1, W02, W12, W22, W32, W42, W52, 4);                               \
    DOT6(qb0, W03, W13, W23, W33, W43, W53, 0);                               \
    DOT6(qb1, W03, W13, W23, W33, W43, W53, 4);                               \
    float mvr, mvz, mvn;                                                      \
    QREDUCE(mvr, mvz, mvn);                                                   \
    float r = sigmoid_fast(xr_c + mvr);                                       \
    float z = sigmoid_fast(xz_c + mvz);                                       \
    float n = tanh_fast(xn_c + mvn + r * mvn);  /* torch quirk */            \
    h = z * (h - n) + n;                                                      \
    if (c < 2) {                                                              \
      op[0] = h;                                                              \
      *(_Float16*)(smh + (WB) + wofs) = (_Float16)h;                          \
    }                                                                         \
    asm volatile("s_waitcnt lgkmcnt(0)\n\ts_barrier" ::: "memory");           \
    xr_c = xr_n; xz_c = xz_n; xn_c = xn_n;                                    \
    xq += (size_t)BATCH * NG;                                                 \
    op += (size_t)BATCH * NH;                                                 \
  } while (0)

  for (int t0 = 0; t0 < S_LEN; t0 += 8) {
    if (t0 && (t0 & 31) == 0) FLAGWAIT36(flags + t0);  // rows t0..t0+35
    for (int u = 0; u < 4; ++u) {
      GSTEP(0, 576);
      GSTEP(576, 0);
    }
  }
#undef GSTEP

  if (c < 2) out[(size_t)S_LEN * BATCH * NH + (size_t)b * NH + jmine] = h;
}

extern "C" void kernel_launch(void* const* d_in, const int* in_sizes, int n_in,
                              void* d_out, int out_size, void* d_ws, size_t ws_size,
                              hipStream_t stream) {
  const float* input = (const float*)d_in[0];
  const float* W_ih  = (const float*)d_in[1];
  const float* W_hh  = (const float*)d_in[2];
  const float* b_ih  = (const float*)d_in[3];
  const float* b_hh  = (const float*)d_in[4];
  float* out = (float*)d_out;

  const size_t SB = (size_t)S_LEN * BATCH;           // 65536
  const size_t xp_b = SB * NG * 4;                   // 192 MiB
  const size_t w_b  = (size_t)128 * NG * 4;          // 384 KiB each

  char* p = (char*)d_ws;
  float*    xp    = (float*)p;                p += xp_b;
  half2_t*  whh3  = (half2_t*)p;              p += w_b;
  half2_t*  wih3  = (half2_t*)p;              p += w_b;
  float*    bias  = (float*)p;                p += (size_t)NG * 4;
  uintptr_t fp_ = (((uintptr_t)p) + 127) & ~(uintptr_t)127;
  int*      flags = (int*)fp_;                // 2064 ints (2048 + 16 sentinels)

  const int prep_items = 2 * 128 * NG + NG + XPB + 16;
  prep_w_kernel<<<(prep_items + 255) / 256, 256, 0, stream>>>(W_ih, W_hh, b_ih, b_hh,
                                                              whh3, wih3, bias, flags);
  fused_kernel<<<GRUB + XPB, 512, 0, stream>>>(input, wih3, bias, xp, whh3, out, flags);
  (void)out_size; (void)n_in; (void)in_sizes; (void)ws_size;
}